// Round 4
// baseline (224.104 us; speedup 1.0000x reference)
//
#include <hip/hip_runtime.h>
#include <hip/hip_bf16.h>
#include <hip/hip_cooperative_groups.h>
#include <math.h>

namespace cg = cooperative_groups;

// Problem constants
#define BB   256
#define INW  512
#define HH   1024
#define OUTW 512
#define SS   512
#define WD   256
#define P_READ  262
#define P_WRITE 774
#define RW_LD   1056   // 272 (read pad) + 784 (write pad)
#define W_OFF   272

#define NBLK 256
#define NTHR 512
#define GRIDTH (NBLK * NTHR)   // 131072 threads, 2048 waves

typedef __attribute__((ext_vector_type(8))) short bf16x8;
typedef __attribute__((ext_vector_type(4))) float f32x4;

__device__ __forceinline__ float sigmoidf(float x) { return 1.f / (1.f + expf(-x)); }
__device__ __forceinline__ float softplusf(float x) { return (x > 20.f) ? x : log1pf(expf(x)); }
__device__ __forceinline__ float b2f(short s) {
    union { float f; unsigned u; } c; c.u = ((unsigned)(unsigned short)s) << 16; return c.f;
}
__device__ __forceinline__ float wave_sum(float v) {
    #pragma unroll
    for (int off = 32; off > 0; off >>= 1) v += __shfl_down(v, off, 64);
    return v;
}

// conversion segment sizes
#define N_WIH (3072*512)
#define N_WRW (RW_LD*1024)
#define N_WO  (512*1280)
#define N_X   (256*512)
#define N_MB  (512*256)
#define N_MT  (256*512)
#define N_BIA 3072
#define N_BRW RW_LD
#define N_TOT (N_WIH+N_WRW+N_WO+N_X+N_MB+N_MT+N_BIA+N_BRW)

struct Params {
    const float *x, *W_ih, *b_ih, *b_hh, *W_read, *b_read, *W_write, *b_write, *W_out, *b_out, *mem;
    float *rpwp, *bias_c, *bias_rw, *mem_norm, *out;
    __hip_bfloat16 *x_b, *Wih_c, *Wrw_p, *Wo_b, *mem_b, *memT_b, *hrv;
};

__device__ __forceinline__ void st_bf2(__hip_bfloat16* dst, float a, float b) {
    __hip_bfloat162 h; h.x = __float2bfloat16(a); h.y = __float2bfloat16(b);
    *reinterpret_cast<__hip_bfloat162*>(dst) = h;
}

// generic dual-acc MFMA tile: C[bm:bm+16, bn:bn+16] (+)= A[.., kofs:kofs+K] * B^T + bias
__device__ __forceinline__ void tile_gemm(const __hip_bfloat16* __restrict__ A, int lda,
                                          const __hip_bfloat16* __restrict__ B, int ldb,
                                          int kofs, int K, const float* __restrict__ bias,
                                          float* __restrict__ C, int ldc,
                                          int bm, int bn, int lane, bool accum)
{
    const int r = lane & 15, q = lane >> 4;
    const __hip_bfloat16* ap = A + (size_t)(bm + r) * lda + kofs + q * 8;
    const __hip_bfloat16* bp = B + (size_t)(bn + r) * ldb + kofs + q * 8;
    const int K2 = (K >> 6) << 5;
    f32x4 a0 = {0.f,0.f,0.f,0.f}, a1 = a0;
    #pragma unroll 4
    for (int k = 0; k < K2; k += 32)
        a0 = __builtin_amdgcn_mfma_f32_16x16x32_bf16(
            *reinterpret_cast<const bf16x8*>(ap + k),
            *reinterpret_cast<const bf16x8*>(bp + k), a0, 0, 0, 0);
    #pragma unroll 4
    for (int k = K2; k < K; k += 32)
        a1 = __builtin_amdgcn_mfma_f32_16x16x32_bf16(
            *reinterpret_cast<const bf16x8*>(ap + k),
            *reinterpret_cast<const bf16x8*>(bp + k), a1, 0, 0, 0);
    const int col = bn + r;
    const float bv = bias ? bias[col] : 0.f;
    #pragma unroll
    for (int j = 0; j < 4; ++j) {
        int m = bm + q * 4 + j;
        float v = a0[j] + a1[j] + bv;
        if (accum) v += C[(size_t)m * ldc + col];
        C[(size_t)m * ldc + col] = v;
    }
}

__global__ __launch_bounds__(NTHR, 2)
void mega(Params p)
{
    __shared__ float s_red[8], s_red2[8];
    __shared__ float s_keyr[256], s_keyw[256];
    __shared__ float s_bufr[512], s_bufw[512];
    __shared__ float s_p1[512], s_p2[512];

    cg::grid_group grid = cg::this_grid();
    const int t = threadIdx.x;
    const int lane = t & 63;
    const int wid = blockIdx.x * 8 + (t >> 6);

    // ================= P0: mem norms + convert all =================
    {
        // two mem rows per block
        int s = 2 * blockIdx.x + (t >> 8);
        float v = p.mem[(size_t)s * WD + (t & 255)];
        float vv = wave_sum(v * v);
        if ((t & 63) == 0) s_red[t >> 6] = vv;
        __syncthreads();
        if (t == 0)   p.mem_norm[s] = fmaxf(sqrtf(s_red[0]+s_red[1]+s_red[2]+s_red[3]), 1e-8f);
        if (t == 256) p.mem_norm[s] = fmaxf(sqrtf(s_red[4]+s_red[5]+s_red[6]+s_red[7]), 1e-8f);

        const long NP = N_TOT >> 1;
        for (long ii = (long)blockIdx.x * NTHR + t; ii < NP; ii += GRIDTH) {
            long i = ii * 2;
            if (i < N_WIH) {
                int r = (int)(i >> 9), c = (int)(i & 511);
                int sr = r < 1024 ? r : r + 1024;
                const float* s0 = p.W_ih + (size_t)sr * 768 + c;
                st_bf2(p.Wih_c + i, s0[0], s0[1]);
                continue;
            }
            i -= N_WIH;
            if (i < N_WRW) {
                int r = (int)(i >> 10), c = (int)(i & 1023);
                float a0 = 0.f, a1 = 0.f;
                if (r < W_OFF) {
                    if (r < P_READ) { const float* s0 = p.W_read + (size_t)r * 1024 + c; a0 = s0[0]; a1 = s0[1]; }
                } else {
                    int wr = r - W_OFF;
                    if (wr < P_WRITE) { const float* s0 = p.W_write + (size_t)wr * 1024 + c; a0 = s0[0]; a1 = s0[1]; }
                }
                st_bf2(p.Wrw_p + i, a0, a1);
                continue;
            }
            i -= N_WRW;
            if (i < N_WO) { st_bf2(p.Wo_b + i, p.W_out[i], p.W_out[i + 1]); continue; }
            i -= N_WO;
            if (i < N_X)  { st_bf2(p.x_b + i, p.x[i], p.x[i + 1]); continue; }
            i -= N_X;
            if (i < N_MB) { st_bf2(p.mem_b + i, p.mem[i], p.mem[i + 1]); continue; }
            i -= N_MB;
            if (i < N_MT) {
                int w = (int)(i >> 9), s0 = (int)(i & 511);
                st_bf2(p.memT_b + i, p.mem[(size_t)s0 * 256 + w], p.mem[(size_t)(s0 + 1) * 256 + w]);
                continue;
            }
            i -= N_MT;
            if (i < N_BIA) {
                #pragma unroll
                for (int u = 0; u < 2; ++u) {
                    long r = i + u;
                    long sr = r < 1024 ? r : r + 1024;
                    p.bias_c[r] = p.b_ih[sr] + p.b_hh[sr];
                }
                continue;
            }
            i -= N_BIA;
            {
                #pragma unroll
                for (int u = 0; u < 2; ++u) {
                    long r = i + u;
                    float v2 = 0.f;
                    if (r < W_OFF) { if (r < P_READ) v2 = p.b_read[r]; }
                    else { long wr = r - W_OFF; if (wr < P_WRITE) v2 = p.b_write[wr]; }
                    p.bias_rw[r] = v2;
                }
            }
        }
    }
    grid.sync();

    // ================= P1: gates GEMM + LSTM -> hrv[:,0:1024] =================
    if (wid < 1024) {
        const int bn = (wid & 63) * 16;     // j tile
        const int bm = (wid >> 6) * 16;     // b tile
        const int r = lane & 15, q = lane >> 4;
        const __hip_bfloat16* ap = p.x_b + (size_t)(bm + r) * INW + q * 8;
        const __hip_bfloat16* bi = p.Wih_c + (size_t)(bn + r) * INW + q * 8;
        const __hip_bfloat16* bg = bi + (size_t)1024 * INW;
        const __hip_bfloat16* bo = bi + (size_t)2048 * INW;
        f32x4 ai = {0.f,0.f,0.f,0.f}, ag = ai, ao = ai;
        #pragma unroll
        for (int k = 0; k < INW; k += 32) {
            bf16x8 a = *reinterpret_cast<const bf16x8*>(ap + k);
            ai = __builtin_amdgcn_mfma_f32_16x16x32_bf16(a, *reinterpret_cast<const bf16x8*>(bi + k), ai, 0, 0, 0);
            ag = __builtin_amdgcn_mfma_f32_16x16x32_bf16(a, *reinterpret_cast<const bf16x8*>(bg + k), ag, 0, 0, 0);
            ao = __builtin_amdgcn_mfma_f32_16x16x32_bf16(a, *reinterpret_cast<const bf16x8*>(bo + k), ao, 0, 0, 0);
        }
        const int j = bn + r;
        const float bii = p.bias_c[j], big = p.bias_c[1024 + j], bio = p.bias_c[2048 + j];
        #pragma unroll
        for (int jj = 0; jj < 4; ++jj) {
            int b = bm + q * 4 + jj;
            float c = sigmoidf(ai[jj] + bii) * tanhf(ag[jj] + big);
            p.hrv[(size_t)b * 1280 + j] = __float2bfloat16(sigmoidf(ao[jj] + bio) * tanhf(c));
        }
    }
    grid.sync();

    // ================= P2: rpwp GEMM  ||  out h-part GEMM (K=1024) =================
    if (wid < 1056) {
        int nt = wid % 66, mt = wid / 66;
        tile_gemm(p.hrv, 1280, p.Wrw_p, 1024, 0, 1024, p.bias_rw,
                  p.rpwp, RW_LD, mt * 16, nt * 16, lane, false);
    } else if (wid < 1568) {
        int o = wid - 1056;
        int nt = o & 31, mt = o >> 5;
        tile_gemm(p.hrv, 1280, p.Wo_b, 1280, 0, 1024, p.b_out,
                  p.out, OUTW, mt * 16, nt * 16, lane, false);
    }
    grid.sync();

    // ================= P3: per-batch addressing + rv =================
    {
        const int b = blockIdx.x;
        const float* pr = p.rpwp + (size_t)b * RW_LD;
        const float* pw = pr + W_OFF;

        float kv;
        if (t < 256) { kv = pr[t]; s_keyr[t] = kv; }
        else         { kv = pw[t - 256]; s_keyw[t - 256] = kv; }
        float vv = wave_sum(kv * kv);
        if ((t & 63) == 0) s_red[t >> 6] = vv;
        __syncthreads();
        float knr = fmaxf(sqrtf(s_red[0]+s_red[1]+s_red[2]+s_red[3]), 1e-8f);
        float knw = fmaxf(sqrtf(s_red[4]+s_red[5]+s_red[6]+s_red[7]), 1e-8f);

        // header params
        float beta_r = softplusf(pr[WD]);
        float gate_r = sigmoidf(pr[WD + 1]);
        float r0 = pr[WD+2], r1 = pr[WD+3], r2 = pr[WD+4];
        float rmx = fmaxf(r0, fmaxf(r1, r2));
        float re0 = expf(r0-rmx), re1 = expf(r1-rmx), re2 = expf(r2-rmx);
        float rinv = 1.f / (re0+re1+re2);
        float shr0 = re0*rinv, shr1 = re1*rinv, shr2 = re2*rinv;
        float gamma_r = 1.f + softplusf(pr[WD + 5]);

        float beta_w = softplusf(pw[WD]);
        float gate_w = sigmoidf(pw[WD + 1]);
        float w0 = pw[WD+2], w1 = pw[WD+3], w2 = pw[WD+4];
        float wmx = fmaxf(w0, fmaxf(w1, w2));
        float we0 = expf(w0-wmx), we1 = expf(w1-wmx), we2 = expf(w2-wmx);
        float winv = 1.f / (we0+we1+we2);
        float shw0 = we0*winv, shw1 = we1*winv, shw2 = we2*winv;
        float gamma_w = 1.f + softplusf(pw[WD + 5]);

        // num dots vs mem_b (slot = t)
        float nr = 0.f, nw = 0.f;
        {
            const bf16x8* mrow = reinterpret_cast<const bf16x8*>(p.mem_b + (size_t)t * WD);
            const float4* kr4 = reinterpret_cast<const float4*>(s_keyr);
            const float4* kw4 = reinterpret_cast<const float4*>(s_keyw);
            #pragma unroll 8
            for (int kk = 0; kk < 32; ++kk) {
                bf16x8 m8 = mrow[kk];
                float4 ka = kr4[2*kk], kb = kr4[2*kk+1];
                float4 wa = kw4[2*kk], wb = kw4[2*kk+1];
                float m0=b2f(m8[0]),m1=b2f(m8[1]),m2=b2f(m8[2]),m3=b2f(m8[3]);
                float m4=b2f(m8[4]),m5=b2f(m8[5]),m6=b2f(m8[6]),m7=b2f(m8[7]);
                nr += ka.x*m0+ka.y*m1+ka.z*m2+ka.w*m3 + kb.x*m4+kb.y*m5+kb.z*m6+kb.w*m7;
                nw += wa.x*m0+wa.y*m1+wa.z*m2+wa.w*m3 + wb.x*m4+wb.y*m5+wb.z*m6+wb.w*m7;
            }
        }
        float mni = 1.f / p.mem_norm[t];
        float sim_r = nr * mni / knr * beta_r;
        float sim_w = nw * mni / knw * beta_w;

        // softmax over 512 (both at once)
        float mr = sim_r, mw = sim_w;
        {   // redpair max
            #pragma unroll
            for (int off = 32; off > 0; off >>= 1) { mr = fmaxf(mr, __shfl_down(mr, off, 64)); mw = fmaxf(mw, __shfl_down(mw, off, 64)); }
            int widb = t >> 6;
            __syncthreads();
            if ((t & 63) == 0) { s_red[widb] = mr; s_red2[widb] = mw; }
            __syncthreads();
            mr = fmaxf(fmaxf(fmaxf(s_red[0],s_red[1]),fmaxf(s_red[2],s_red[3])),fmaxf(fmaxf(s_red[4],s_red[5]),fmaxf(s_red[6],s_red[7])));
            mw = fmaxf(fmaxf(fmaxf(s_red2[0],s_red2[1]),fmaxf(s_red2[2],s_red2[3])),fmaxf(fmaxf(s_red2[4],s_red2[5]),fmaxf(s_red2[6],s_red2[7])));
        }
        float exr = expf(sim_r - mr), exw = expf(sim_w - mw);
        float sr = exr, sw = exw;
        {   // redpair sum
            #pragma unroll
            for (int off = 32; off > 0; off >>= 1) { sr += __shfl_down(sr, off, 64); sw += __shfl_down(sw, off, 64); }
            int widb = t >> 6;
            __syncthreads();
            if ((t & 63) == 0) { s_red[widb] = sr; s_red2[widb] = sw; }
            __syncthreads();
            sr = s_red[0]+s_red[1]+s_red[2]+s_red[3]+s_red[4]+s_red[5]+s_red[6]+s_red[7];
            sw = s_red2[0]+s_red2[1]+s_red2[2]+s_red2[3]+s_red2[4]+s_red2[5]+s_red2[6]+s_red2[7];
        }
        float cwr = exr / sr, cww = exw / sw;

        float onehot = (t == 0) ? 1.f : 0.f;
        float gwr = gate_r * cwr + (1.f - gate_r) * onehot;
        float gww = gate_w * cww + (1.f - gate_w) * onehot;
        __syncthreads();
        s_bufr[t] = gwr; s_bufw[t] = gww;
        __syncthreads();

        int tm = (t + SS - 1) & (SS - 1), tp = (t + 1) & (SS - 1);
        float swr = shr0 * s_bufr[tm] + shr1 * gwr + shr2 * s_bufr[tp];
        float sww = shw0 * s_bufw[tm] + shw1 * gww + shw2 * s_bufw[tp];

        float spr = powf(swr, gamma_r), spw = powf(sww, gamma_w);
        float ssr = spr, ssw = spw;
        {   // redpair sum
            #pragma unroll
            for (int off = 32; off > 0; off >>= 1) { ssr += __shfl_down(ssr, off, 64); ssw += __shfl_down(ssw, off, 64); }
            int widb = t >> 6;
            __syncthreads();
            if ((t & 63) == 0) { s_red[widb] = ssr; s_red2[widb] = ssw; }
            __syncthreads();
            ssr = s_red[0]+s_red[1]+s_red[2]+s_red[3]+s_red[4]+s_red[5]+s_red[6]+s_red[7];
            ssw = s_red2[0]+s_red2[1]+s_red2[2]+s_red2[3]+s_red2[4]+s_red2[5]+s_red2[6]+s_red2[7];
        }
        float rfin = spr / (ssr + 1e-6f);
        float wfin = spw / (ssw + 1e-6f);
        float prod = rfin * wfin;

        // t3 (all threads get it)
        float tp3 = prod, dmy = 0.f;
        {
            #pragma unroll
            for (int off = 32; off > 0; off >>= 1) { tp3 += __shfl_down(tp3, off, 64); dmy += 0.f; }
            int widb = t >> 6;
            __syncthreads();
            if ((t & 63) == 0) s_red[widb] = tp3;
            __syncthreads();
            tp3 = s_red[0]+s_red[1]+s_red[2]+s_red[3]+s_red[4]+s_red[5]+s_red[6]+s_red[7];
        }
        __syncthreads();
        s_bufr[t] = rfin; s_bufw[t] = prod;
        __syncthreads();

        // rv dots vs memT_b, split s-range across the two half-blocks
        int w = t & 255, half = t >> 8;
        float p1 = 0.f, p2 = 0.f;
        {
            const bf16x8* mTrow = reinterpret_cast<const bf16x8*>(p.memT_b + (size_t)w * SS + half * 256);
            const float4* br4 = reinterpret_cast<const float4*>(s_bufr + half * 256);
            const float4* bw4 = reinterpret_cast<const float4*>(s_bufw + half * 256);
            #pragma unroll 8
            for (int kk = 0; kk < 32; ++kk) {
                bf16x8 m8 = mTrow[kk];
                float4 ra = br4[2*kk], rb = br4[2*kk+1];
                float4 wa = bw4[2*kk], wb = bw4[2*kk+1];
                float m0=b2f(m8[0]),m1=b2f(m8[1]),m2=b2f(m8[2]),m3=b2f(m8[3]);
                float m4=b2f(m8[4]),m5=b2f(m8[5]),m6=b2f(m8[6]),m7=b2f(m8[7]);
                p1 += ra.x*m0+ra.y*m1+ra.z*m2+ra.w*m3 + rb.x*m4+rb.y*m5+rb.z*m6+rb.w*m7;
                p2 += wa.x*m0+wa.y*m1+wa.z*m2+wa.w*m3 + wb.x*m4+wb.y*m5+wb.z*m6+wb.w*m7;
            }
        }
        s_p1[t] = p1; s_p2[t] = p2;
        __syncthreads();
        if (t < 256) {
            float P1 = s_p1[t] + s_p1[t + 256];
            float P2 = s_p2[t] + s_p2[t + 256];
            float e = sigmoidf(pw[P_READ + t]);
            float a = tanhf(pw[P_READ + WD + t]);
            float rv = P1 - e * P2 + a * tp3;
            p.hrv[(size_t)b * 1280 + 1024 + t] = __float2bfloat16(rv);
        }
    }
    grid.sync();

    // ================= P4: out rv-part (K=256), accumulate =================
    if (wid < 512) {
        int nt = wid & 31, mt = wid >> 5;
        tile_gemm(p.hrv, 1280, p.Wo_b, 1280, 1024, 256, nullptr,
                  p.out, OUTW, mt * 16, nt * 16, lane, true);
    }
}

// ---------------- host launcher ----------------
extern "C" void kernel_launch(void* const* d_in, const int* in_sizes, int n_in,
                              void* d_out, int out_size, void* d_ws, size_t ws_size,
                              hipStream_t stream)
{
    float* ws = (float*)d_ws;
    Params prm;
    prm.x       = (const float*)d_in[0];
    prm.W_ih    = (const float*)d_in[1];
    prm.b_ih    = (const float*)d_in[2];
    prm.b_hh    = (const float*)d_in[4];
    prm.W_read  = (const float*)d_in[5];
    prm.b_read  = (const float*)d_in[6];
    prm.W_write = (const float*)d_in[7];
    prm.b_write = (const float*)d_in[8];
    prm.W_out   = (const float*)d_in[9];
    prm.b_out   = (const float*)d_in[10];
    prm.mem     = (const float*)d_in[11];

    prm.rpwp     = ws;                    // 270336
    prm.bias_c   = ws + 270336;           // 3072
    prm.bias_rw  = ws + 273408;           // 1056
    prm.mem_norm = ws + 274464;           // 512
    __hip_bfloat16* bfb = (__hip_bfloat16*)(ws + 274976);
    prm.x_b    = bfb;                     // 131072
    prm.Wih_c  = bfb + 131072;            // 1572864
    prm.Wrw_p  = bfb + 1703936;           // 1081344
    prm.Wo_b   = bfb + 2785280;           // 655360
    prm.mem_b  = bfb + 3440640;           // 131072
    prm.memT_b = bfb + 3571712;           // 131072
    prm.hrv    = bfb + 3702784;           // 327680
    prm.out    = (float*)d_out;

    void* kargs[] = { &prm };
    hipLaunchCooperativeKernel((const void*)mega, dim3(NBLK), dim3(NTHR), kargs, 0, stream);
}

// Round 5
// 77.955 us; speedup vs baseline: 2.8748x; 2.8748x over previous
//
#include <hip/hip_runtime.h>
#include <hip/hip_bf16.h>
#include <math.h>

// Problem constants
#define BB   256
#define INW  512
#define HH   1024
#define OUTW 512
#define SS   512
#define WD   256
#define P_READ  262
#define P_WRITE 774
#define RW_LD   1056   // 272 (read pad) + 784 (write pad)
#define W_OFF   272

typedef __attribute__((ext_vector_type(8))) short bf16x8;
typedef __attribute__((ext_vector_type(4))) float f32x4;

__device__ __forceinline__ float sigmoidf(float x) { return 1.f / (1.f + expf(-x)); }
__device__ __forceinline__ float softplusf(float x) { return (x > 20.f) ? x : log1pf(expf(x)); }
__device__ __forceinline__ float b2f(short s) {
    union { float f; unsigned u; } c; c.u = ((unsigned)(unsigned short)s) << 16; return c.f;
}
__device__ __forceinline__ unsigned short f2b(float f) {   // RNE, matches __float2bfloat16 for finite vals
    union { float f; unsigned u; } c; c.f = f;
    return (unsigned short)((c.u + 0x7FFFu + ((c.u >> 16) & 1u)) >> 16);
}
__device__ __forceinline__ void st_bf4(__hip_bfloat16* d, float a, float b, float c, float e) {
    ushort4 u; u.x = f2b(a); u.y = f2b(b); u.z = f2b(c); u.w = f2b(e);
    *reinterpret_cast<ushort4*>(d) = u;
}
__device__ __forceinline__ float wave_sum(float v) {
    #pragma unroll
    for (int off = 32; off > 0; off >>= 1) v += __shfl_down(v, off, 64);
    return v;
}

// conversion segment sizes (all multiples of 4)
#define N_WIH (3072*512)
#define N_WRW (RW_LD*1024)
#define N_WO  (512*1280)
#define N_X   (256*512)
#define N_MB  (512*256)
#define N_MT  (256*512)
#define N_BIA 3072
#define N_BRW RW_LD
#define N_TOT (N_WIH+N_WRW+N_WO+N_X+N_MB+N_MT+N_BIA+N_BRW)
#define NB_CVT ((N_TOT/4 + 255) / 256)

// ================= K1: convert/pack (4-wide) + mem norms + biases =================
__global__ __launch_bounds__(256)
void convert_all(const float* __restrict__ W_ih, const float* __restrict__ b_ih,
                 const float* __restrict__ b_hh,
                 const float* __restrict__ W_read, const float* __restrict__ b_read,
                 const float* __restrict__ W_write, const float* __restrict__ b_write,
                 const float* __restrict__ W_out, const float* __restrict__ x,
                 const float* __restrict__ mem,
                 __hip_bfloat16* __restrict__ Wih_c, __hip_bfloat16* __restrict__ Wrw_p,
                 __hip_bfloat16* __restrict__ Wo_b, __hip_bfloat16* __restrict__ x_b,
                 __hip_bfloat16* __restrict__ mem_b, __hip_bfloat16* __restrict__ memT_b,
                 float* __restrict__ bias_c, float* __restrict__ bias_rw,
                 float* __restrict__ mem_norm)
{
    if (blockIdx.x >= NB_CVT) {
        // one mem row norm per block
        __shared__ float red[4];
        int s = blockIdx.x - NB_CVT;
        float v = mem[(size_t)s * WD + threadIdx.x];
        float vv = wave_sum(v * v);
        if ((threadIdx.x & 63) == 0) red[threadIdx.x >> 6] = vv;
        __syncthreads();
        if (threadIdx.x == 0)
            mem_norm[s] = fmaxf(sqrtf(red[0] + red[1] + red[2] + red[3]), 1e-8f);
        return;
    }
    long i = ((long)blockIdx.x * 256 + threadIdx.x) * 4;
    if (i >= N_TOT) return;
    if (i < N_WIH) {   // compact i|g|o rows of W_ih, first 512 cols only
        int r = (int)(i >> 9), c = (int)(i & 511);
        int sr = r < 1024 ? r : r + 1024;    // skip f-gate rows
        float4 v = *reinterpret_cast<const float4*>(W_ih + (size_t)sr * 768 + c);
        st_bf4(Wih_c + i, v.x, v.y, v.z, v.w);
        return;
    }
    i -= N_WIH;
    if (i < N_WRW) {   // [Wr padded to 272 ; Ww padded to 784] x 1024
        int r = (int)(i >> 10), c = (int)(i & 1023);
        float4 v = make_float4(0.f, 0.f, 0.f, 0.f);
        if (r < W_OFF) { if (r < P_READ) v = *reinterpret_cast<const float4*>(W_read + (size_t)r * 1024 + c); }
        else { int wr = r - W_OFF; if (wr < P_WRITE) v = *reinterpret_cast<const float4*>(W_write + (size_t)wr * 1024 + c); }
        st_bf4(Wrw_p + i, v.x, v.y, v.z, v.w);
        return;
    }
    i -= N_WRW;
    if (i < N_WO) {
        float4 v = *reinterpret_cast<const float4*>(W_out + i);
        st_bf4(Wo_b + i, v.x, v.y, v.z, v.w);
        return;
    }
    i -= N_WO;
    if (i < N_X) {
        float4 v = *reinterpret_cast<const float4*>(x + i);
        st_bf4(x_b + i, v.x, v.y, v.z, v.w);
        return;
    }
    i -= N_X;
    if (i < N_MB) {
        float4 v = *reinterpret_cast<const float4*>(mem + i);
        st_bf4(mem_b + i, v.x, v.y, v.z, v.w);
        return;
    }
    i -= N_MB;
    if (i < N_MT) {   // transpose gather
        int w = (int)(i >> 9), s = (int)(i & 511);
        st_bf4(memT_b + i, mem[(size_t)s * 256 + w], mem[(size_t)(s + 1) * 256 + w],
               mem[(size_t)(s + 2) * 256 + w], mem[(size_t)(s + 3) * 256 + w]);
        return;
    }
    i -= N_MT;
    if (i < N_BIA) {
        #pragma unroll
        for (int u = 0; u < 4; ++u) {
            long r = i + u;
            long sr = r < 1024 ? r : r + 1024;
            bias_c[r] = b_ih[sr] + b_hh[sr];
        }
        return;
    }
    i -= N_BIA;
    {
        #pragma unroll
        for (int u = 0; u < 4; ++u) {
            long r = i + u;
            float v = 0.f;
            if (r < W_OFF) { if (r < P_READ) v = b_read[r]; }
            else { long wr = r - W_OFF; if (wr < P_WRITE) v = b_write[wr]; }
            bias_rw[r] = v;
        }
    }
}

// ================= K2: gates GEMM + LSTM -> h_b [256][1024] bf16 =================
__global__ __launch_bounds__(64)
void gemm_gates(const __hip_bfloat16* __restrict__ x_b,
                const __hip_bfloat16* __restrict__ Wih_c,
                const float* __restrict__ bias_c,
                __hip_bfloat16* __restrict__ h_b)
{
    const int l = threadIdx.x;
    const int bn = blockIdx.x * 16;
    const int bm = blockIdx.y * 16;
    const int r = l & 15, q = l >> 4;
    const __hip_bfloat16* ap = x_b + (size_t)(bm + r) * INW + q * 8;
    const __hip_bfloat16* bi = Wih_c + (size_t)(bn + r) * INW + q * 8;
    const __hip_bfloat16* bg = bi + (size_t)1024 * INW;
    const __hip_bfloat16* bo = bi + (size_t)2048 * INW;
    f32x4 ai = {0.f,0.f,0.f,0.f}, ag = ai, ao = ai;
    #pragma unroll
    for (int k = 0; k < INW; k += 32) {
        bf16x8 a = *reinterpret_cast<const bf16x8*>(ap + k);
        ai = __builtin_amdgcn_mfma_f32_16x16x32_bf16(a, *reinterpret_cast<const bf16x8*>(bi + k), ai, 0, 0, 0);
        ag = __builtin_amdgcn_mfma_f32_16x16x32_bf16(a, *reinterpret_cast<const bf16x8*>(bg + k), ag, 0, 0, 0);
        ao = __builtin_amdgcn_mfma_f32_16x16x32_bf16(a, *reinterpret_cast<const bf16x8*>(bo + k), ao, 0, 0, 0);
    }
    const int j = bn + r;
    const float bii = bias_c[j], big = bias_c[1024 + j], bio = bias_c[2048 + j];
    #pragma unroll
    for (int jj = 0; jj < 4; ++jj) {
        int b = bm + q * 4 + jj;
        float c = sigmoidf(ai[jj] + bii) * tanhf(ag[jj] + big);
        h_b[(size_t)b * HH + j] = __float2bfloat16(sigmoidf(ao[jj] + bio) * tanhf(c));
    }
}

// ================= K3: dual GEMM (rpwp || out h-part), one launch =================
__device__ __forceinline__ void tile_gemm(const __hip_bfloat16* __restrict__ A, int lda,
                                          const __hip_bfloat16* __restrict__ B, int ldb,
                                          int K, const float* __restrict__ bias,
                                          float* __restrict__ C, int ldc,
                                          int bm, int bn, int lane)
{
    const int r = lane & 15, q = lane >> 4;
    const __hip_bfloat16* ap = A + (size_t)(bm + r) * lda + q * 8;
    const __hip_bfloat16* bp = B + (size_t)(bn + r) * ldb + q * 8;
    const int K2 = K >> 1;
    f32x4 a0 = {0.f,0.f,0.f,0.f}, a1 = a0;
    #pragma unroll 8
    for (int k = 0; k < K2; k += 32) {
        a0 = __builtin_amdgcn_mfma_f32_16x16x32_bf16(
            *reinterpret_cast<const bf16x8*>(ap + k),
            *reinterpret_cast<const bf16x8*>(bp + k), a0, 0, 0, 0);
        a1 = __builtin_amdgcn_mfma_f32_16x16x32_bf16(
            *reinterpret_cast<const bf16x8*>(ap + K2 + k),
            *reinterpret_cast<const bf16x8*>(bp + K2 + k), a1, 0, 0, 0);
    }
    const int col = bn + r;
    const float bv = bias ? bias[col] : 0.f;
    #pragma unroll
    for (int j = 0; j < 4; ++j) {
        int m = bm + q * 4 + j;
        C[(size_t)m * ldc + col] = a0[j] + a1[j] + bv;
    }
}

__global__ __launch_bounds__(64)
void gemm_dual(const __hip_bfloat16* __restrict__ h_b,
               const __hip_bfloat16* __restrict__ Wrw_p,
               const __hip_bfloat16* __restrict__ Wo_b,
               const float* __restrict__ bias_rw, const float* __restrict__ b_out,
               float* __restrict__ rpwp, float* __restrict__ out)
{
    const int bid = blockIdx.x;
    const int lane = threadIdx.x;
    if (bid < 1056) {
        int nt = bid % 66, mt = bid / 66;
        tile_gemm(h_b, HH, Wrw_p, HH, HH, bias_rw, rpwp, RW_LD, mt * 16, nt * 16, lane);
    } else {
        int o = bid - 1056;
        int nt = o & 31, mt = o >> 5;
        tile_gemm(h_b, HH, Wo_b, 1280, HH, b_out, out, OUTW, mt * 16, nt * 16, lane);
    }
}

// ================= K4: per-batch addressing + rv + out rv-part =================
__global__ __launch_bounds__(512)
void addr_rv_out(const float* __restrict__ rpwp, const float* __restrict__ mem_norm,
                 const __hip_bfloat16* __restrict__ mem_b,
                 const __hip_bfloat16* __restrict__ memT_b,
                 const __hip_bfloat16* __restrict__ Wo_b,
                 float* __restrict__ out)
{
    __shared__ float s_red[8], s_red2[8];
    __shared__ __align__(16) float s_keyr[256], s_keyw[256];
    __shared__ __align__(16) float s_bufr[512], s_bufw[512];
    __shared__ float s_p1[512], s_p2[512];
    __shared__ __align__(16) float s_rv[256];

    const int b = blockIdx.x;
    const int t = threadIdx.x;
    const float* pr = rpwp + (size_t)b * RW_LD;
    const float* pw = pr + W_OFF;

    // keys -> LDS + key norms
    float kv;
    if (t < 256) { kv = pr[t]; s_keyr[t] = kv; }
    else         { kv = pw[t - 256]; s_keyw[t - 256] = kv; }
    float vv = wave_sum(kv * kv);
    if ((t & 63) == 0) s_red[t >> 6] = vv;
    __syncthreads();
    float knr = fmaxf(sqrtf(s_red[0]+s_red[1]+s_red[2]+s_red[3]), 1e-8f);
    float knw = fmaxf(sqrtf(s_red[4]+s_red[5]+s_red[6]+s_red[7]), 1e-8f);

    // header params (broadcast)
    float beta_r = softplusf(pr[WD]);
    float gate_r = sigmoidf(pr[WD + 1]);
    float r0 = pr[WD+2], r1 = pr[WD+3], r2 = pr[WD+4];
    float rmx = fmaxf(r0, fmaxf(r1, r2));
    float re0 = expf(r0-rmx), re1 = expf(r1-rmx), re2 = expf(r2-rmx);
    float rinv = 1.f / (re0+re1+re2);
    float shr0 = re0*rinv, shr1 = re1*rinv, shr2 = re2*rinv;
    float gamma_r = 1.f + softplusf(pr[WD + 5]);

    float beta_w = softplusf(pw[WD]);
    float gate_w = sigmoidf(pw[WD + 1]);
    float w0 = pw[WD+2], w1 = pw[WD+3], w2 = pw[WD+4];
    float wmx = fmaxf(w0, fmaxf(w1, w2));
    float we0 = expf(w0-wmx), we1 = expf(w1-wmx), we2 = expf(w2-wmx);
    float winv = 1.f / (we0+we1+we2);
    float shw0 = we0*winv, shw1 = we1*winv, shw2 = we2*winv;
    float gamma_w = 1.f + softplusf(pw[WD + 5]);

    // cosine numerators: slot = t
    float nr = 0.f, nw = 0.f;
    {
        const bf16x8* mrow = reinterpret_cast<const bf16x8*>(mem_b + (size_t)t * WD);
        const float4* kr4 = reinterpret_cast<const float4*>(s_keyr);
        const float4* kw4 = reinterpret_cast<const float4*>(s_keyw);
        #pragma unroll 8
        for (int kk = 0; kk < 32; ++kk) {
            bf16x8 m8 = mrow[kk];
            float4 ka = kr4[2*kk], kb = kr4[2*kk+1];
            float4 wa = kw4[2*kk], wb = kw4[2*kk+1];
            float m0=b2f(m8[0]),m1=b2f(m8[1]),m2=b2f(m8[2]),m3=b2f(m8[3]);
            float m4=b2f(m8[4]),m5=b2f(m8[5]),m6=b2f(m8[6]),m7=b2f(m8[7]);
            nr += ka.x*m0+ka.y*m1+ka.z*m2+ka.w*m3 + kb.x*m4+kb.y*m5+kb.z*m6+kb.w*m7;
            nw += wa.x*m0+wa.y*m1+wa.z*m2+wa.w*m3 + wb.x*m4+wb.y*m5+wb.z*m6+wb.w*m7;
        }
    }
    float mni = 1.f / mem_norm[t];
    float sim_r = nr * mni / knr * beta_r;
    float sim_w = nw * mni / knw * beta_w;

    // paired softmax over 512 slots
    float mr = sim_r, mw = sim_w;
    {
        #pragma unroll
        for (int off = 32; off > 0; off >>= 1) { mr = fmaxf(mr, __shfl_down(mr, off, 64)); mw = fmaxf(mw, __shfl_down(mw, off, 64)); }
        __syncthreads();
        if ((t & 63) == 0) { s_red[t >> 6] = mr; s_red2[t >> 6] = mw; }
        __syncthreads();
        mr = fmaxf(fmaxf(fmaxf(s_red[0],s_red[1]),fmaxf(s_red[2],s_red[3])),fmaxf(fmaxf(s_red[4],s_red[5]),fmaxf(s_red[6],s_red[7])));
        mw = fmaxf(fmaxf(fmaxf(s_red2[0],s_red2[1]),fmaxf(s_red2[2],s_red2[3])),fmaxf(fmaxf(s_red2[4],s_red2[5]),fmaxf(s_red2[6],s_red2[7])));
    }
    float exr = expf(sim_r - mr), exw = expf(sim_w - mw);
    float sr = exr, sw = exw;
    {
        #pragma unroll
        for (int off = 32; off > 0; off >>= 1) { sr += __shfl_down(sr, off, 64); sw += __shfl_down(sw, off, 64); }
        __syncthreads();
        if ((t & 63) == 0) { s_red[t >> 6] = sr; s_red2[t >> 6] = sw; }
        __syncthreads();
        sr = s_red[0]+s_red[1]+s_red[2]+s_red[3]+s_red[4]+s_red[5]+s_red[6]+s_red[7];
        sw = s_red2[0]+s_red2[1]+s_red2[2]+s_red2[3]+s_red2[4]+s_red2[5]+s_red2[6]+s_red2[7];
    }
    float cwr = exr / sr, cww = exw / sw;

    // gate with prev_w = one-hot(0)
    float onehot = (t == 0) ? 1.f : 0.f;
    float gwr = gate_r * cwr + (1.f - gate_r) * onehot;
    float gww = gate_w * cww + (1.f - gate_w) * onehot;
    __syncthreads();
    s_bufr[t] = gwr; s_bufw[t] = gww;
    __syncthreads();

    // cyclic shift
    int tm = (t + SS - 1) & (SS - 1), tp = (t + 1) & (SS - 1);
    float swr = shr0 * s_bufr[tm] + shr1 * gwr + shr2 * s_bufr[tp];
    float sww = shw0 * s_bufw[tm] + shw1 * gww + shw2 * s_bufw[tp];

    // sharpen + normalize
    float spr = powf(swr, gamma_r), spw = powf(sww, gamma_w);
    float ssr = spr, ssw = spw;
    {
        #pragma unroll
        for (int off = 32; off > 0; off >>= 1) { ssr += __shfl_down(ssr, off, 64); ssw += __shfl_down(ssw, off, 64); }
        __syncthreads();
        if ((t & 63) == 0) { s_red[t >> 6] = ssr; s_red2[t >> 6] = ssw; }
        __syncthreads();
        ssr = s_red[0]+s_red[1]+s_red[2]+s_red[3]+s_red[4]+s_red[5]+s_red[6]+s_red[7];
        ssw = s_red2[0]+s_red2[1]+s_red2[2]+s_red2[3]+s_red2[4]+s_red2[5]+s_red2[6]+s_red2[7];
    }
    float rfin = spr / (ssr + 1e-6f);
    float wfin = spw / (ssw + 1e-6f);
    float prod = rfin * wfin;

    // t3 = sum prod (broadcast to all)
    float tp3 = prod;
    {
        #pragma unroll
        for (int off = 32; off > 0; off >>= 1) tp3 += __shfl_down(tp3, off, 64);
        __syncthreads();
        if ((t & 63) == 0) s_red[t >> 6] = tp3;
        __syncthreads();
        tp3 = s_red[0]+s_red[1]+s_red[2]+s_red[3]+s_red[4]+s_red[5]+s_red[6]+s_red[7];
    }
    __syncthreads();
    s_bufr[t] = rfin; s_bufw[t] = prod;
    __syncthreads();

    // rv dots vs memT_b, split s-range across the two half-blocks
    int w = t & 255, half = t >> 8;
    float p1 = 0.f, p2 = 0.f;
    {
        const bf16x8* mTrow = reinterpret_cast<const bf16x8*>(memT_b + (size_t)w * SS + half * 256);
        const float4* br4 = reinterpret_cast<const float4*>(s_bufr + half * 256);
        const float4* bw4 = reinterpret_cast<const float4*>(s_bufw + half * 256);
        #pragma unroll 8
        for (int kk = 0; kk < 32; ++kk) {
            bf16x8 m8 = mTrow[kk];
            float4 ra = br4[2*kk], rb = br4[2*kk+1];
            float4 wa = bw4[2*kk], wb = bw4[2*kk+1];
            float m0=b2f(m8[0]),m1=b2f(m8[1]),m2=b2f(m8[2]),m3=b2f(m8[3]);
            float m4=b2f(m8[4]),m5=b2f(m8[5]),m6=b2f(m8[6]),m7=b2f(m8[7]);
            p1 += ra.x*m0+ra.y*m1+ra.z*m2+ra.w*m3 + rb.x*m4+rb.y*m5+rb.z*m6+rb.w*m7;
            p2 += wa.x*m0+wa.y*m1+wa.z*m2+wa.w*m3 + wb.x*m4+wb.y*m5+wb.z*m6+wb.w*m7;
        }
    }
    s_p1[t] = p1; s_p2[t] = p2;
    __syncthreads();
    if (t < 256) {
        float P1 = s_p1[t] + s_p1[t + 256];
        float P2 = s_p2[t] + s_p2[t + 256];
        float e = sigmoidf(pw[P_READ + t]);
        float a = tanhf(pw[P_READ + WD + t]);
        s_rv[t] = P1 - e * P2 + a * tp3;
    }
    __syncthreads();

    // out rv-part GEMV: out[b][o] += sum_w rv[w] * Wo[o][1024+w]
    {
        const int o = t;
        const bf16x8* wrow = reinterpret_cast<const bf16x8*>(Wo_b + (size_t)o * 1280 + 1024);
        const float4* rv4 = reinterpret_cast<const float4*>(s_rv);
        float acc = 0.f;
        #pragma unroll 8
        for (int kk = 0; kk < 32; ++kk) {
            bf16x8 m8 = wrow[kk];
            float4 ra = rv4[2*kk], rb = rv4[2*kk+1];
            acc += ra.x*b2f(m8[0])+ra.y*b2f(m8[1])+ra.z*b2f(m8[2])+ra.w*b2f(m8[3])
                 + rb.x*b2f(m8[4])+rb.y*b2f(m8[5])+rb.z*b2f(m8[6])+rb.w*b2f(m8[7]);
        }
        out[(size_t)b * OUTW + o] += acc;
    }
}

// ---------------- host launcher ----------------
extern "C" void kernel_launch(void* const* d_in, const int* in_sizes, int n_in,
                              void* d_out, int out_size, void* d_ws, size_t ws_size,
                              hipStream_t stream)
{
    const float* x       = (const float*)d_in[0];
    const float* W_ih    = (const float*)d_in[1];
    const float* b_ih    = (const float*)d_in[2];
    const float* b_hh    = (const float*)d_in[4];
    const float* W_read  = (const float*)d_in[5];
    const float* b_read  = (const float*)d_in[6];
    const float* W_write = (const float*)d_in[7];
    const float* b_write = (const float*)d_in[8];
    const float* W_out   = (const float*)d_in[9];
    const float* b_out   = (const float*)d_in[10];
    const float* mem     = (const float*)d_in[11];

    float* ws = (float*)d_ws;
    float* rpwp     = ws;                 // 270336
    float* bias_c   = ws + 270336;        // 3072
    float* bias_rw  = ws + 273408;        // 1056
    float* mem_norm = ws + 274464;        // 512
    __hip_bfloat16* bfb = (__hip_bfloat16*)(ws + 274976);
    __hip_bfloat16* x_b    = bfb;                 // 131072
    __hip_bfloat16* Wih_c  = bfb + 131072;        // 1572864
    __hip_bfloat16* Wrw_p  = bfb + 1703936;       // 1081344
    __hip_bfloat16* Wo_b   = bfb + 2785280;       // 655360
    __hip_bfloat16* mem_b  = bfb + 3440640;       // 131072
    __hip_bfloat16* memT_b = bfb + 3571712;       // 131072
    __hip_bfloat16* h_b    = bfb + 3702784;       // 262144
    float* out = (float*)d_out;

    // K1: convert/pack + mem norms + biases
    convert_all<<<NB_CVT + SS, 256, 0, stream>>>(
        W_ih, b_ih, b_hh, W_read, b_read, W_write, b_write, W_out, x, mem,
        Wih_c, Wrw_p, Wo_b, x_b, mem_b, memT_b, bias_c, bias_rw, mem_norm);
    // K2: gates GEMM + LSTM -> h_b
    gemm_gates<<<dim3(64, 16), 64, 0, stream>>>(x_b, Wih_c, bias_c, h_b);
    // K3: rpwp GEMM || out h-part GEMM
    gemm_dual<<<1568, 64, 0, stream>>>(h_b, Wrw_p, Wo_b, bias_rw, b_out, rpwp, out);
    // K4: addressing + rv + out rv-part
    addr_rv_out<<<BB, 512, 0, stream>>>(rpwp, mem_norm, mem_b, memT_b, Wo_b, out);
}